// Round 11
// baseline (342.003 us; speedup 1.0000x reference)
//
#include <hip/hip_runtime.h>
#include <hip/hip_bf16.h>
#include <hip/hip_cooperative_groups.h>

namespace cg = cooperative_groups;

#define NN 50000
#define NE 600000
#define IN_DIM 128
#define HC 128      // H*C
#define NH 4
#define NC 32
#define NEG_SLOPE 0.2f

#define NTHR 256
#define NTILE 196           // ceil(NN/256) scan tiles
#define WT_TOTAL 86016
#define NG32 1563           // ceil(NN/32): one 32-row group per block
#define GHIST 2344          // ceil(NE/256)
#define NGAT16 3125         // ceil(NN/16): 16 nodes per block (4 per wave, slot-per-node)

typedef __attribute__((ext_vector_type(8))) short short8;
typedef __attribute__((ext_vector_type(4))) float floatx4;
typedef __attribute__((ext_vector_type(8))) unsigned short ushort8v;

__device__ __forceinline__ float bf2f(unsigned short u) {
    return __uint_as_float(((unsigned)u) << 16);
}
__device__ __forceinline__ unsigned short f2bf(float f) {
    unsigned u = __float_as_uint(f);
    unsigned r = (u + 0x7FFFu + ((u >> 16) & 1u)) >> 16;   // RNE
    return (unsigned short)r;
}

// 16-row GEMM from an LDS x-tile: one row-group, NTC col-groups, K=128.
// Wt in fragment order [ks][colgroup][quad][l16][8] -> Wt wave-loads are 1 KB
// contiguous. mfma(A=Wt frag, B=x frag) -> D[m=channel][n=node].
template<int OD, int NTC, int PITX, int PITO>
__device__ __forceinline__ void gemm16_lds(
    const unsigned short (* __restrict__ xt)[PITX], const unsigned short* __restrict__ Wt,
    const float* __restrict__ b, unsigned short (* __restrict__ tile)[PITO],
    int c016, int lane) {
    int quad = lane >> 4, l16 = lane & 15;
    floatx4 acc[NTC];
    #pragma unroll
    for (int j = 0; j < NTC; ++j) acc[j] = (floatx4){0.f, 0.f, 0.f, 0.f};
    int lidx = (quad * 16 + l16) * 8;

    #pragma unroll
    for (int ks = 0; ks < 4; ++ks) {
        int kb = ks * 32 + quad * 8;
        short8 xb = *(const short8*)&xt[l16][kb];
        #pragma unroll
        for (int tc = 0; tc < NTC; ++tc) {
            int grp = ks * (OD / 16) + c016 + tc;
            short8 af = *(const short8*)&Wt[grp * 512 + lidx];
            acc[tc] = __builtin_amdgcn_mfma_f32_16x16x32_bf16(af, xb, acc[tc], 0, 0, 0);
        }
    }

    #pragma unroll
    for (int tc = 0; tc < NTC; ++tc) {
        int cbase = (c016 + tc) * 16 + quad * 4;
        float4 bv = *(const float4*)&b[cbase];
        ushort4 pk = {f2bf(acc[tc][0] + bv.x), f2bf(acc[tc][1] + bv.y),
                      f2bf(acc[tc][2] + bv.z), f2bf(acc[tc][3] + bv.w)};
        *(ushort4*)&tile[l16][cbase] = pk;
    }
}

// cooperative store of a 32x128 bf16 tile (pitch 136) by 128 threads, full lines
__device__ __forceinline__ void store_tile128(
    const unsigned short (* __restrict__ tile)[136],
    unsigned short* __restrict__ y, int n0, int pt) {
    #pragma unroll
    for (int s = 0; s < 4; ++s) {
        int idx = s * 128 + pt;
        int node = idx >> 4, t16 = idx & 15;
        if (n0 + node < NN)
            *(ushort8v*)&y[(size_t)(n0 + node) * 128 + t16 * 8] =
                *(const ushort8v*)&tile[node][t16 * 8];
    }
}

// ---------------- fused GATv2(l) + GEMM(l+1), slot-per-node ----------------
// Each 16-lane slot owns ONE node. 4-deep gather prefetch (depth-8 and
// setprio both measured neutral; degree-binning negative: the edge loop sits
// at the random-gather service floor). gat epilogue writes the 128-wide bf16
// row to an LDS x-tile; after a barrier the SAME block runs the next layer's
// dual GEMM for its 16 rows from LDS (waves 0/1: h halves; 2/3: skip).
template<int SOD>
__global__ __launch_bounds__(256) void k_gat_gemm(
    const unsigned short* __restrict__ h, const int* __restrict__ rowptr,
    const int* __restrict__ csr_src, const float* __restrict__ att,
    const float* __restrict__ gbias, const unsigned short* __restrict__ gskip,
    const unsigned short* __restrict__ WtA, const float* __restrict__ linb,
    unsigned short* __restrict__ yh,
    const unsigned short* __restrict__ WtB, const float* __restrict__ skipb,
    unsigned short* __restrict__ yskip) {
    __shared__ unsigned short xt[16][136];
    __shared__ unsigned short th[16][136];
    __shared__ unsigned short ts[16][136];

    int lane = threadIdx.x & 63;
    int wid = threadIdx.x >> 6;
    int slot = lane >> 4, t = lane & 15;
    int lbase = slot << 4;
    int nloc = wid * 4 + slot;
    int nv = blockIdx.x * 16 + nloc;
    bool valid = nv < NN;
    int n = valid ? nv : NN - 1;

    // residual row prefetch (hides under the edge loop)
    ushort8v skv = *(const ushort8v*)(gskip + (size_t)n * HC + t * 8);

    int beg = rowptr[n], end = rowptr[n + 1];
    int deg = end - beg;
    int idv = 0;
    if (t < deg) idv = csr_src[beg + t];

    ushort8v hdv = *(const ushort8v*)(h + (size_t)n * HC + t * 8);
    float hd[8], av[8];
    #pragma unroll
    for (int c = 0; c < 8; ++c) hd[c] = bf2f(hdv[c]);
    float4 av0 = ((const float4*)att)[t * 2];
    float4 av1 = ((const float4*)att)[t * 2 + 1];
    av[0] = av0.x; av[1] = av0.y; av[2] = av0.z; av[3] = av0.w;
    av[4] = av1.x; av[5] = av1.y; av[6] = av1.z; av[7] = av1.w;

    float K = 0.f;
    #pragma unroll
    for (int c = 0; c < 8; ++c) K = fmaf(hd[c], av[c], K);

    const unsigned short* hp = h + t * 8;
    int id0 = __shfl(idv, lbase + 0, 64);
    int id1 = __shfl(idv, lbase + 1, 64);
    int id2 = __shfl(idv, lbase + 2, 64);
    int id3 = __shfl(idv, lbase + 3, 64);
    ushort8v g0 = 0, g1 = 0, g2 = 0, g3 = 0;
    if (deg > 0) g0 = *(const ushort8v*)(hp + id0);
    if (deg > 1) g1 = *(const ushort8v*)(hp + id1);
    if (deg > 2) g2 = *(const ushort8v*)(hp + id2);
    if (deg > 3) g3 = *(const ushort8v*)(hp + id3);

    float l = 0.f;
    float acc[8] = {};

    auto gstep = [&](ushort8v& G, int k) {
        float hs[8];
        float S1 = K, S2 = 0.f;
        #pragma unroll
        for (int c = 0; c < 8; ++c) {
            float hsv = bf2f(G[c]);
            hs[c] = hsv;
            S1 = fmaf(hsv, av[c], S1);
            S2 = fmaf(fabsf(hsv + hd[c]), av[c], S2);
        }
        int kn = k + 4;
        if (kn < deg) {                 // refill this slot, 4 steps ahead
            int idn = (kn < 16) ? __shfl(idv, lbase + kn, 64) : csr_src[beg + kn];
            G = *(const ushort8v*)(hp + idn);
        }
        float part = fmaf(0.6f, S1, 0.4f * S2);
        part += __shfl_xor(part, 1, 64);
        part += __shfl_xor(part, 2, 64);
        float p = __expf(part);
        #pragma unroll
        for (int c = 0; c < 8; ++c) acc[c] = fmaf(p, hs[c], acc[c]);
        l += p;
    };

    int k = 0;
    if (deg > 0) for (;;) {
        gstep(g0, k); if (++k >= deg) break;
        gstep(g1, k); if (++k >= deg) break;
        gstep(g2, k); if (++k >= deg) break;
        gstep(g3, k); if (++k >= deg) break;
    }

    float inv = 1.f / fmaxf(l, 1e-16f);
    float4 bv0 = ((const float4*)gbias)[t * 2];
    float4 bv1 = ((const float4*)gbias)[t * 2 + 1];
    float bb[8] = {bv0.x, bv0.y, bv0.z, bv0.w, bv1.x, bv1.y, bv1.z, bv1.w};
    ushort8v ov;
    #pragma unroll
    for (int c = 0; c < 8; ++c) {
        float r = acc[c] * inv + bb[c] + bf2f(skv[c]);
        r = r > 0.f ? r : (__expf(r) - 1.f);   // ELU
        ov[c] = f2bf(r);
    }
    *(ushort8v*)&xt[nloc][t * 8] = ov;       // duplicate row for invalid: defined, stores guarded

    __syncthreads();

    // ---- next-layer GEMM from LDS (16 rows) ----
    if (wid < 2)           gemm16_lds<128, 4, 136, 136>(xt, WtA, linb, th, wid * 4, lane);
    else if (SOD == 128)   gemm16_lds<128, 4, 136, 136>(xt, WtB, skipb, ts, (wid - 2) * 4, lane);
    else                   gemm16_lds<32, 1, 136, 136>(xt, WtB, skipb, ts, wid - 2, lane);

    __syncthreads();

    // ---- cooperative full-line stores ----
    int p = threadIdx.x;
    {
        int node = p >> 4, t16 = p & 15;
        int gn = blockIdx.x * 16 + node;
        if (gn < NN)
            *(ushort8v*)&yh[(size_t)gn * 128 + t16 * 8] = *(const ushort8v*)&th[node][t16 * 8];
    }
    if (SOD == 128) {
        int node = p >> 4, t16 = p & 15;
        int gn = blockIdx.x * 16 + node;
        if (gn < NN)
            *(ushort8v*)&yskip[(size_t)gn * 128 + t16 * 8] = *(const ushort8v*)&ts[node][t16 * 8];
    } else {
        if (p < 64) {
            int node = p >> 2, t4 = p & 3;
            int gn = blockIdx.x * 16 + node;
            if (gn < NN)
                *(ushort8v*)&yskip[(size_t)gn * 32 + t4 * 8] = *(const ushort8v*)&ts[node][t4 * 8];
        }
    }
}

// ---------------- final-layer GATv2 (head-mean, fp32 out) ----------------
__global__ __launch_bounds__(256) void k_gat_last(
    const unsigned short* __restrict__ h, const int* __restrict__ rowptr,
    const int* __restrict__ csr_src, const float* __restrict__ att,
    const float* __restrict__ bias, const unsigned short* __restrict__ skip,
    float* __restrict__ out) {
    int lane = threadIdx.x & 63;
    int wid = threadIdx.x >> 6;
    int slot = lane >> 4, t = lane & 15;
    int lbase = slot << 4;

    int nv = blockIdx.x * 16 + wid * 4 + slot;
    bool valid = nv < NN;
    int n = valid ? nv : NN - 1;

    ushort8v skv = 0;
    if (t < 4) skv = *(const ushort8v*)(skip + (size_t)n * NC + t * 8);

    int beg = rowptr[n], end = rowptr[n + 1];
    int deg = end - beg;
    int idv = 0;
    if (t < deg) idv = csr_src[beg + t];

    ushort8v hdv = *(const ushort8v*)(h + (size_t)n * HC + t * 8);
    float hd[8], av[8];
    #pragma unroll
    for (int c = 0; c < 8; ++c) hd[c] = bf2f(hdv[c]);
    float4 av0 = ((const float4*)att)[t * 2];
    float4 av1 = ((const float4*)att)[t * 2 + 1];
    av[0] = av0.x; av[1] = av0.y; av[2] = av0.z; av[3] = av0.w;
    av[4] = av1.x; av[5] = av1.y; av[6] = av1.z; av[7] = av1.w;

    float K = 0.f;
    #pragma unroll
    for (int c = 0; c < 8; ++c) K = fmaf(hd[c], av[c], K);

    const unsigned short* hp = h + t * 8;
    int id0 = __shfl(idv, lbase + 0, 64);
    int id1 = __shfl(idv, lbase + 1, 64);
    int id2 = __shfl(idv, lbase + 2, 64);
    int id3 = __shfl(idv, lbase + 3, 64);
    ushort8v g0 = 0, g1 = 0, g2 = 0, g3 = 0;
    if (deg > 0) g0 = *(const ushort8v*)(hp + id0);
    if (deg > 1) g1 = *(const ushort8v*)(hp + id1);
    if (deg > 2) g2 = *(const ushort8v*)(hp + id2);
    if (deg > 3) g3 = *(const ushort8v*)(hp + id3);

    float l = 0.f;
    float acc[8] = {};

    auto gstep = [&](ushort8v& G, int k) {
        float hs[8];
        float S1 = K, S2 = 0.f;
        #pragma unroll
        for (int c = 0; c < 8; ++c) {
            float hsv = bf2f(G[c]);
            hs[c] = hsv;
            S1 = fmaf(hsv, av[c], S1);
            S2 = fmaf(fabsf(hsv + hd[c]), av[c], S2);
        }
        int kn = k + 4;
        if (kn < deg) {
            int idn = (kn < 16) ? __shfl(idv, lbase + kn, 64) : csr_src[beg + kn];
            G = *(const ushort8v*)(hp + idn);
        }
        float part = fmaf(0.6f, S1, 0.4f * S2);
        part += __shfl_xor(part, 1, 64);
        part += __shfl_xor(part, 2, 64);
        float p = __expf(part);
        #pragma unroll
        for (int c = 0; c < 8; ++c) acc[c] = fmaf(p, hs[c], acc[c]);
        l += p;
    };

    int k = 0;
    if (deg > 0) for (;;) {
        gstep(g0, k); if (++k >= deg) break;
        gstep(g1, k); if (++k >= deg) break;
        gstep(g2, k); if (++k >= deg) break;
        gstep(g3, k); if (++k >= deg) break;
    }

    float inv = 1.f / fmaxf(l, 1e-16f);
    float o[8];
    #pragma unroll
    for (int c = 0; c < 8; ++c) o[c] = acc[c] * inv;

    // head-mean within the slot: heads for local channel c live at t, t+4, t+8, t+12
    float r4[8], r8[8], r12[8];
    #pragma unroll
    for (int c = 0; c < 8; ++c) {
        r4[c]  = __shfl_down(o[c], 4, 16);
        r8[c]  = __shfl_down(o[c], 8, 16);
        r12[c] = __shfl_down(o[c], 12, 16);
    }
    if (t < 4 && valid) {
        float* op = out + (size_t)n * NC + t * 8;
        float rr[8];
        #pragma unroll
        for (int c = 0; c < 8; ++c) {
            rr[c] = 0.25f * (o[c] + r4[c] + r8[c] + r12[c])
                  + bias[t * 8 + c] + bf2f(skv[c]);
        }
        *(float4*)op = (float4){rr[0], rr[1], rr[2], rr[3]};
        *(float4*)(op + 4) = (float4){rr[4], rr[5], rr[6], rr[7]};
    }
}

// ---------------- phase kernels ----------------

// transpose weights to bf16 fragment-ordered Wt AND zero deg.
__global__ void k_prep(const float* __restrict__ W0, const float* __restrict__ S0,
                       const float* __restrict__ W1, const float* __restrict__ S1,
                       const float* __restrict__ W2, const float* __restrict__ S2,
                       unsigned short* __restrict__ wt, int* __restrict__ deg) {
    int idx = blockIdx.x * blockDim.x + threadIdx.x;
    if (idx < WT_TOTAL) {
        if (idx < 81920) {          // five OD=128 matrices, 16384 shorts each
            int r = idx >> 14;
            const float* W = (r == 0) ? W0 : (r == 1) ? S0 : (r == 2) ? W1 : (r == 3) ? S1 : W2;
            int off = idx & 16383;
            int j = off & 7, l16 = (off >> 3) & 15, quad = (off >> 7) & 3;
            int cg = (off >> 9) & 7, ks = off >> 12;
            int k = ks * 32 + quad * 8 + j;
            int col = cg * 16 + l16;
            wt[idx] = f2bf(W[(size_t)k * 128 + col]);
        } else {                    // S2: OD=32, 4096 shorts
            int off = idx - 81920;
            int j = off & 7, l16 = (off >> 3) & 15, quad = (off >> 7) & 3;
            int cg = (off >> 9) & 1, ks = off >> 10;
            int k = ks * 32 + quad * 8 + j;
            int col = cg * 16 + l16;
            wt[idx] = f2bf(S2[(size_t)k * 32 + col]);
        }
        return;
    }
    int i = idx - WT_TOTAL;
    if (i < NN) deg[i] = 0;
}

// layer-0 dual GEMM + histogram, one dispatch.
// The block's 32-row fp32 x-tile is CONTIGUOUS (16 KB): stage it to LDS with
// fully-coalesced loads + in-register f2bf, then MFMA fragments from LDS.
// Histogram SAVES the atomic's return as rank[e] (coalesced stream) so the
// scatter phase needs no cursor atomics.
__global__ __launch_bounds__(256) void k_gemm0_hist(
    const float* __restrict__ x,
    const unsigned short* __restrict__ Wta, const float* __restrict__ ba, unsigned short* __restrict__ ya,
    const unsigned short* __restrict__ Wtb, const float* __restrict__ bb, unsigned short* __restrict__ yb,
    const int* __restrict__ dst, int* __restrict__ deg, int* __restrict__ rank) {
    __shared__ unsigned short xt[32][136];
    __shared__ unsigned short tA[32][136];
    __shared__ unsigned short tB[32][136];
    int b = blockIdx.x;
    if (b < NG32) {
        int n0 = b * 32;
        // stage: 32 rows x 128 ch fp32 = 1024 float4; 256 threads x 4, coalesced
        #pragma unroll
        for (int s = 0; s < 4; ++s) {
            int i = s * 256 + threadIdx.x;
            int row = i >> 5, c4 = i & 31;
            int rr = (n0 + row < NN) ? n0 + row : NN - 1;
            float4 v = *(const float4*)&x[(size_t)rr * IN_DIM + c4 * 4];
            ushort4 pk = {f2bf(v.x), f2bf(v.y), f2bf(v.z), f2bf(v.w)};
            *(ushort4*)&xt[row][c4 * 4] = pk;
        }
        __syncthreads();
        int wid = threadIdx.x >> 6, lane = threadIdx.x & 63;
        if (wid < 2) {
            gemm16_lds<128, 4, 136, 136>(xt, Wta, ba, tA, wid * 4, lane);
            gemm16_lds<128, 4, 136, 136>(xt + 16, Wta, ba, tA + 16, wid * 4, lane);
        } else {
            gemm16_lds<128, 4, 136, 136>(xt, Wtb, bb, tB, (wid - 2) * 4, lane);
            gemm16_lds<128, 4, 136, 136>(xt + 16, Wtb, bb, tB + 16, (wid - 2) * 4, lane);
        }
        __syncthreads();
        int pt = threadIdx.x & 127;
        if (threadIdx.x < 128) store_tile128(tA, ya, n0, pt);
        else                   store_tile128(tB, yb, n0, pt);
    } else {
        int e = (b - NG32) * 256 + threadIdx.x;
        if (e < NE) rank[e] = atomicAdd(&deg[dst[e]], 1);
    }
}

// single cooperative dispatch: tile scan -> tile-offset apply -> scatter.
// Replaces scan1 + scan23 + scatter (saves 2 dispatch boundaries).
__global__ __launch_bounds__(NTHR) void k_csr(
    const int* __restrict__ deg, int* __restrict__ rowptr,
    int* __restrict__ blocksum,
    const int* __restrict__ src, const int* __restrict__ dst,
    const int* __restrict__ rank, int* __restrict__ csr_src) {
    cg::grid_group grid = cg::this_grid();
    __shared__ int sh[NTHR];
    int b = blockIdx.x, t = threadIdx.x;
    int i = b * NTHR + t;

    // phase 1: per-tile inclusive scan of deg
    int d = (i < NN) ? deg[i] : 0;
    sh[t] = d;
    __syncthreads();
    #pragma unroll
    for (int off = 1; off < NTHR; off <<= 1) {
        int v = (t >= off) ? sh[t - off] : 0;
        __syncthreads();
        sh[t] += v;
        __syncthreads();
    }
    if (i < NN) rowptr[i + 1] = sh[t];           // tile-local inclusive prefix
    if (t == NTHR - 1) blocksum[b] = sh[t];

    grid.sync();

    // phase 2: every block redundantly scans the 196 blocksums; apply offset
    int v = (t < NTILE) ? blocksum[t] : 0;
    sh[t] = v;
    __syncthreads();
    #pragma unroll
    for (int off = 1; off < NTHR; off <<= 1) {
        int u = (t >= off) ? sh[t - off] : 0;
        __syncthreads();
        sh[t] += u;
        __syncthreads();
    }
    int tile_off = (b > 0) ? sh[b - 1] : 0;
    if (i < NN) rowptr[i + 1] += tile_off;
    if (b == 0 && t == 0) rowptr[0] = 0;

    grid.sync();

    // phase 3: atomic-free scatter, grid-stride (entries premultiplied by HC)
    for (int e = b * NTHR + t; e < NE; e += NTILE * NTHR) {
        int dd = dst[e];
        csr_src[rowptr[dd] + rank[e]] = src[e] * HC;
    }
}

extern "C" void kernel_launch(void* const* d_in, const int* in_sizes, int n_in,
                              void* d_out, int out_size, void* d_ws, size_t ws_size,
                              hipStream_t stream) {
    const float* x0 = (const float*)d_in[0];
    const int* ei = (const int*)d_in[1];
    const int* src = ei;
    const int* dst = ei + NE;

    unsigned short* H0 = (unsigned short*)d_ws;              // NN*HC bf16
    unsigned short* S0 = H0 + (size_t)NN * HC;               // NN*HC bf16
    unsigned short* H1 = S0 + (size_t)NN * HC;               // NN*HC bf16
    unsigned short* S1 = H1 + (size_t)NN * HC;               // NN*HC bf16
    int* deg     = (int*)(S1 + (size_t)NN * HC);             // NN
    int* rowptr  = deg + NN;                                 // NN+1
    int* blocksum = rowptr + NN + 1;                         // NTILE
    int* rank    = blocksum + NTILE;                         // NE
    uintptr_t pa = (uintptr_t)(rank + NE);
    pa = (pa + 15) & ~(uintptr_t)15;
    unsigned short* wt = (unsigned short*)pa;                // WT_TOTAL bf16
    int* csr_src = (int*)(wt + WT_TOTAL);                    // NE

    unsigned short* wtW[3] = {wt, wt + 32768, wt + 65536};
    unsigned short* wtS[3] = {wt + 16384, wt + 49152, wt + 81920};

    // 1) prep: fragment-order transpose of weights, zero deg
    k_prep<<<(WT_TOTAL + NN + 255) / 256, 256, 0, stream>>>(
        (const float*)d_in[2], (const float*)d_in[6],
        (const float*)d_in[8], (const float*)d_in[12],
        (const float*)d_in[14], (const float*)d_in[18], wt, deg);

    // 2) layer-0 dual GEMM (LDS-staged coalesced x) + histogram (saves rank)
    k_gemm0_hist<<<NG32 + GHIST, 256, 0, stream>>>(
        x0, wtW[0], (const float*)d_in[3], H0,
        wtS[0], (const float*)d_in[7], S0, dst, deg, rank);

    // 3) CSR build: one cooperative dispatch (scan + offsets + scatter)
    {
        void* args[] = {(void*)&deg, (void*)&rowptr, (void*)&blocksum,
                        (void*)&src, (void*)&dst, (void*)&rank, (void*)&csr_src};
        hipLaunchCooperativeKernel((void*)k_csr, dim3(NTILE), dim3(NTHR),
                                   args, 0, stream);
    }

    // 4) gat(l0) + gemm(l1) fused: reads H0/S0, writes H1/S1
    k_gat_gemm<128><<<NGAT16, 256, 0, stream>>>(
        H0, rowptr, csr_src,
        (const float*)d_in[4], (const float*)d_in[5], S0,
        wtW[1], (const float*)d_in[9], H1,
        wtS[1], (const float*)d_in[13], S1);

    // 5) gat(l1) + gemm(l2) fused: reads H1/S1, writes H0/S0 (skip 32-wide)
    k_gat_gemm<32><<<NGAT16, 256, 0, stream>>>(
        H1, rowptr, csr_src,
        (const float*)d_in[10], (const float*)d_in[11], S1,
        wtW[2], (const float*)d_in[15], H0,
        wtS[2], (const float*)d_in[19], S0);

    // 6) final gat(l2): head-mean + skip, fp32 out
    k_gat_last<<<NGAT16, 256, 0, stream>>>(
        H0, rowptr, csr_src,
        (const float*)d_in[16], (const float*)d_in[17], S0, (float*)d_out);
}

// Round 12
// 257.141 us; speedup vs baseline: 1.3300x; 1.3300x over previous
//
#include <hip/hip_runtime.h>
#include <hip/hip_bf16.h>

#define NN 50000
#define NE 600000
#define IN_DIM 128
#define HC 128      // H*C
#define NH 4
#define NC 32
#define NEG_SLOPE 0.2f

#define NTHR 256
#define NTILE 196           // ceil(NN/256) scan tiles
#define WT_TOTAL 86016
#define NG32 1563           // ceil(NN/32): one 32-row group per block
#define GHIST 2344          // ceil(NE/256)
#define NGAT16 3125         // ceil(NN/16): 16 nodes per block (4 per wave, slot-per-node)

typedef __attribute__((ext_vector_type(8))) short short8;
typedef __attribute__((ext_vector_type(4))) float floatx4;
typedef __attribute__((ext_vector_type(8))) unsigned short ushort8v;

__device__ __forceinline__ float bf2f(unsigned short u) {
    return __uint_as_float(((unsigned)u) << 16);
}
__device__ __forceinline__ unsigned short f2bf(float f) {
    unsigned u = __float_as_uint(f);
    unsigned r = (u + 0x7FFFu + ((u >> 16) & 1u)) >> 16;   // RNE
    return (unsigned short)r;
}

// 16-row GEMM from an LDS x-tile: one row-group, NTC col-groups, K=128.
// Wt in fragment order [ks][colgroup][quad][l16][8] -> Wt wave-loads are 1 KB
// contiguous. mfma(A=Wt frag, B=x frag) -> D[m=channel][n=node].
template<int OD, int NTC, int PITX, int PITO>
__device__ __forceinline__ void gemm16_lds(
    const unsigned short (* __restrict__ xt)[PITX], const unsigned short* __restrict__ Wt,
    const float* __restrict__ b, unsigned short (* __restrict__ tile)[PITO],
    int c016, int lane) {
    int quad = lane >> 4, l16 = lane & 15;
    floatx4 acc[NTC];
    #pragma unroll
    for (int j = 0; j < NTC; ++j) acc[j] = (floatx4){0.f, 0.f, 0.f, 0.f};
    int lidx = (quad * 16 + l16) * 8;

    #pragma unroll
    for (int ks = 0; ks < 4; ++ks) {
        int kb = ks * 32 + quad * 8;
        short8 xb = *(const short8*)&xt[l16][kb];
        #pragma unroll
        for (int tc = 0; tc < NTC; ++tc) {
            int grp = ks * (OD / 16) + c016 + tc;
            short8 af = *(const short8*)&Wt[grp * 512 + lidx];
            acc[tc] = __builtin_amdgcn_mfma_f32_16x16x32_bf16(af, xb, acc[tc], 0, 0, 0);
        }
    }

    #pragma unroll
    for (int tc = 0; tc < NTC; ++tc) {
        int cbase = (c016 + tc) * 16 + quad * 4;
        float4 bv = *(const float4*)&b[cbase];
        ushort4 pk = {f2bf(acc[tc][0] + bv.x), f2bf(acc[tc][1] + bv.y),
                      f2bf(acc[tc][2] + bv.z), f2bf(acc[tc][3] + bv.w)};
        *(ushort4*)&tile[l16][cbase] = pk;
    }
}

// cooperative store of a 32x128 bf16 tile (pitch 136) by 128 threads, full lines
__device__ __forceinline__ void store_tile128(
    const unsigned short (* __restrict__ tile)[136],
    unsigned short* __restrict__ y, int n0, int pt) {
    #pragma unroll
    for (int s = 0; s < 4; ++s) {
        int idx = s * 128 + pt;
        int node = idx >> 4, t16 = idx & 15;
        if (n0 + node < NN)
            *(ushort8v*)&y[(size_t)(n0 + node) * 128 + t16 * 8] =
                *(const ushort8v*)&tile[node][t16 * 8];
    }
}

// ---------------- fused GATv2(l) + GEMM(l+1), slot-per-node ----------------
// Each 16-lane slot owns ONE node. 4-deep gather prefetch (depth-8 and
// setprio both measured neutral; degree-binning negative: the edge loop sits
// at the random-gather service floor). gat epilogue writes the 128-wide bf16
// row to an LDS x-tile; after a barrier the SAME block runs the next layer's
// dual GEMM for its 16 rows from LDS (waves 0/1: h halves; 2/3: skip).
template<int SOD>
__global__ __launch_bounds__(256) void k_gat_gemm(
    const unsigned short* __restrict__ h, const int* __restrict__ rowptr,
    const int* __restrict__ csr_src, const float* __restrict__ att,
    const float* __restrict__ gbias, const unsigned short* __restrict__ gskip,
    const unsigned short* __restrict__ WtA, const float* __restrict__ linb,
    unsigned short* __restrict__ yh,
    const unsigned short* __restrict__ WtB, const float* __restrict__ skipb,
    unsigned short* __restrict__ yskip) {
    __shared__ unsigned short xt[16][136];
    __shared__ unsigned short th[16][136];
    __shared__ unsigned short ts[16][136];

    int lane = threadIdx.x & 63;
    int wid = threadIdx.x >> 6;
    int slot = lane >> 4, t = lane & 15;
    int lbase = slot << 4;
    int nloc = wid * 4 + slot;
    int nv = blockIdx.x * 16 + nloc;
    bool valid = nv < NN;
    int n = valid ? nv : NN - 1;

    // residual row prefetch (hides under the edge loop)
    ushort8v skv = *(const ushort8v*)(gskip + (size_t)n * HC + t * 8);

    int beg = rowptr[n], end = rowptr[n + 1];
    int deg = end - beg;
    int idv = 0;
    if (t < deg) idv = csr_src[beg + t];

    ushort8v hdv = *(const ushort8v*)(h + (size_t)n * HC + t * 8);
    float hd[8], av[8];
    #pragma unroll
    for (int c = 0; c < 8; ++c) hd[c] = bf2f(hdv[c]);
    float4 av0 = ((const float4*)att)[t * 2];
    float4 av1 = ((const float4*)att)[t * 2 + 1];
    av[0] = av0.x; av[1] = av0.y; av[2] = av0.z; av[3] = av0.w;
    av[4] = av1.x; av[5] = av1.y; av[6] = av1.z; av[7] = av1.w;

    float K = 0.f;
    #pragma unroll
    for (int c = 0; c < 8; ++c) K = fmaf(hd[c], av[c], K);

    const unsigned short* hp = h + t * 8;
    int id0 = __shfl(idv, lbase + 0, 64);
    int id1 = __shfl(idv, lbase + 1, 64);
    int id2 = __shfl(idv, lbase + 2, 64);
    int id3 = __shfl(idv, lbase + 3, 64);
    ushort8v g0 = 0, g1 = 0, g2 = 0, g3 = 0;
    if (deg > 0) g0 = *(const ushort8v*)(hp + id0);
    if (deg > 1) g1 = *(const ushort8v*)(hp + id1);
    if (deg > 2) g2 = *(const ushort8v*)(hp + id2);
    if (deg > 3) g3 = *(const ushort8v*)(hp + id3);

    float l = 0.f;
    float acc[8] = {};

    auto gstep = [&](ushort8v& G, int k) {
        float hs[8];
        float S1 = K, S2 = 0.f;
        #pragma unroll
        for (int c = 0; c < 8; ++c) {
            float hsv = bf2f(G[c]);
            hs[c] = hsv;
            S1 = fmaf(hsv, av[c], S1);
            S2 = fmaf(fabsf(hsv + hd[c]), av[c], S2);
        }
        int kn = k + 4;
        if (kn < deg) {                 // refill this slot, 4 steps ahead
            int idn = (kn < 16) ? __shfl(idv, lbase + kn, 64) : csr_src[beg + kn];
            G = *(const ushort8v*)(hp + idn);
        }
        float part = fmaf(0.6f, S1, 0.4f * S2);
        part += __shfl_xor(part, 1, 64);
        part += __shfl_xor(part, 2, 64);
        float p = __expf(part);
        #pragma unroll
        for (int c = 0; c < 8; ++c) acc[c] = fmaf(p, hs[c], acc[c]);
        l += p;
    };

    int k = 0;
    if (deg > 0) for (;;) {
        gstep(g0, k); if (++k >= deg) break;
        gstep(g1, k); if (++k >= deg) break;
        gstep(g2, k); if (++k >= deg) break;
        gstep(g3, k); if (++k >= deg) break;
    }

    float inv = 1.f / fmaxf(l, 1e-16f);
    float4 bv0 = ((const float4*)gbias)[t * 2];
    float4 bv1 = ((const float4*)gbias)[t * 2 + 1];
    float bb[8] = {bv0.x, bv0.y, bv0.z, bv0.w, bv1.x, bv1.y, bv1.z, bv1.w};
    ushort8v ov;
    #pragma unroll
    for (int c = 0; c < 8; ++c) {
        float r = acc[c] * inv + bb[c] + bf2f(skv[c]);
        r = r > 0.f ? r : (__expf(r) - 1.f);   // ELU
        ov[c] = f2bf(r);
    }
    *(ushort8v*)&xt[nloc][t * 8] = ov;       // duplicate row for invalid: defined, stores guarded

    __syncthreads();

    // ---- next-layer GEMM from LDS (16 rows) ----
    if (wid < 2)           gemm16_lds<128, 4, 136, 136>(xt, WtA, linb, th, wid * 4, lane);
    else if (SOD == 128)   gemm16_lds<128, 4, 136, 136>(xt, WtB, skipb, ts, (wid - 2) * 4, lane);
    else                   gemm16_lds<32, 1, 136, 136>(xt, WtB, skipb, ts, wid - 2, lane);

    __syncthreads();

    // ---- cooperative full-line stores ----
    int p = threadIdx.x;
    {
        int node = p >> 4, t16 = p & 15;
        int gn = blockIdx.x * 16 + node;
        if (gn < NN)
            *(ushort8v*)&yh[(size_t)gn * 128 + t16 * 8] = *(const ushort8v*)&th[node][t16 * 8];
    }
    if (SOD == 128) {
        int node = p >> 4, t16 = p & 15;
        int gn = blockIdx.x * 16 + node;
        if (gn < NN)
            *(ushort8v*)&yskip[(size_t)gn * 128 + t16 * 8] = *(const ushort8v*)&ts[node][t16 * 8];
    } else {
        if (p < 64) {
            int node = p >> 2, t4 = p & 3;
            int gn = blockIdx.x * 16 + node;
            if (gn < NN)
                *(ushort8v*)&yskip[(size_t)gn * 32 + t4 * 8] = *(const ushort8v*)&ts[node][t4 * 8];
        }
    }
}

// ---------------- final-layer GATv2 (head-mean, fp32 out) ----------------
__global__ __launch_bounds__(256) void k_gat_last(
    const unsigned short* __restrict__ h, const int* __restrict__ rowptr,
    const int* __restrict__ csr_src, const float* __restrict__ att,
    const float* __restrict__ bias, const unsigned short* __restrict__ skip,
    float* __restrict__ out) {
    int lane = threadIdx.x & 63;
    int wid = threadIdx.x >> 6;
    int slot = lane >> 4, t = lane & 15;
    int lbase = slot << 4;

    int nv = blockIdx.x * 16 + wid * 4 + slot;
    bool valid = nv < NN;
    int n = valid ? nv : NN - 1;

    ushort8v skv = 0;
    if (t < 4) skv = *(const ushort8v*)(skip + (size_t)n * NC + t * 8);

    int beg = rowptr[n], end = rowptr[n + 1];
    int deg = end - beg;
    int idv = 0;
    if (t < deg) idv = csr_src[beg + t];

    ushort8v hdv = *(const ushort8v*)(h + (size_t)n * HC + t * 8);
    float hd[8], av[8];
    #pragma unroll
    for (int c = 0; c < 8; ++c) hd[c] = bf2f(hdv[c]);
    float4 av0 = ((const float4*)att)[t * 2];
    float4 av1 = ((const float4*)att)[t * 2 + 1];
    av[0] = av0.x; av[1] = av0.y; av[2] = av0.z; av[3] = av0.w;
    av[4] = av1.x; av[5] = av1.y; av[6] = av1.z; av[7] = av1.w;

    float K = 0.f;
    #pragma unroll
    for (int c = 0; c < 8; ++c) K = fmaf(hd[c], av[c], K);

    const unsigned short* hp = h + t * 8;
    int id0 = __shfl(idv, lbase + 0, 64);
    int id1 = __shfl(idv, lbase + 1, 64);
    int id2 = __shfl(idv, lbase + 2, 64);
    int id3 = __shfl(idv, lbase + 3, 64);
    ushort8v g0 = 0, g1 = 0, g2 = 0, g3 = 0;
    if (deg > 0) g0 = *(const ushort8v*)(hp + id0);
    if (deg > 1) g1 = *(const ushort8v*)(hp + id1);
    if (deg > 2) g2 = *(const ushort8v*)(hp + id2);
    if (deg > 3) g3 = *(const ushort8v*)(hp + id3);

    float l = 0.f;
    float acc[8] = {};

    auto gstep = [&](ushort8v& G, int k) {
        float hs[8];
        float S1 = K, S2 = 0.f;
        #pragma unroll
        for (int c = 0; c < 8; ++c) {
            float hsv = bf2f(G[c]);
            hs[c] = hsv;
            S1 = fmaf(hsv, av[c], S1);
            S2 = fmaf(fabsf(hsv + hd[c]), av[c], S2);
        }
        int kn = k + 4;
        if (kn < deg) {
            int idn = (kn < 16) ? __shfl(idv, lbase + kn, 64) : csr_src[beg + kn];
            G = *(const ushort8v*)(hp + idn);
        }
        float part = fmaf(0.6f, S1, 0.4f * S2);
        part += __shfl_xor(part, 1, 64);
        part += __shfl_xor(part, 2, 64);
        float p = __expf(part);
        #pragma unroll
        for (int c = 0; c < 8; ++c) acc[c] = fmaf(p, hs[c], acc[c]);
        l += p;
    };

    int k = 0;
    if (deg > 0) for (;;) {
        gstep(g0, k); if (++k >= deg) break;
        gstep(g1, k); if (++k >= deg) break;
        gstep(g2, k); if (++k >= deg) break;
        gstep(g3, k); if (++k >= deg) break;
    }

    float inv = 1.f / fmaxf(l, 1e-16f);
    float o[8];
    #pragma unroll
    for (int c = 0; c < 8; ++c) o[c] = acc[c] * inv;

    // head-mean within the slot: heads for local channel c live at t, t+4, t+8, t+12
    float r4[8], r8[8], r12[8];
    #pragma unroll
    for (int c = 0; c < 8; ++c) {
        r4[c]  = __shfl_down(o[c], 4, 16);
        r8[c]  = __shfl_down(o[c], 8, 16);
        r12[c] = __shfl_down(o[c], 12, 16);
    }
    if (t < 4 && valid) {
        float* op = out + (size_t)n * NC + t * 8;
        float rr[8];
        #pragma unroll
        for (int c = 0; c < 8; ++c) {
            rr[c] = 0.25f * (o[c] + r4[c] + r8[c] + r12[c])
                  + bias[t * 8 + c] + bf2f(skv[c]);
        }
        *(float4*)op = (float4){rr[0], rr[1], rr[2], rr[3]};
        *(float4*)(op + 4) = (float4){rr[4], rr[5], rr[6], rr[7]};
    }
}

// ---------------- phase kernels ----------------

// transpose weights to bf16 fragment-ordered Wt AND zero deg.
__global__ void k_prep(const float* __restrict__ W0, const float* __restrict__ S0,
                       const float* __restrict__ W1, const float* __restrict__ S1,
                       const float* __restrict__ W2, const float* __restrict__ S2,
                       unsigned short* __restrict__ wt, int* __restrict__ deg) {
    int idx = blockIdx.x * blockDim.x + threadIdx.x;
    if (idx < WT_TOTAL) {
        if (idx < 81920) {          // five OD=128 matrices, 16384 shorts each
            int r = idx >> 14;
            const float* W = (r == 0) ? W0 : (r == 1) ? S0 : (r == 2) ? W1 : (r == 3) ? S1 : W2;
            int off = idx & 16383;
            int j = off & 7, l16 = (off >> 3) & 15, quad = (off >> 7) & 3;
            int cg = (off >> 9) & 7, ks = off >> 12;
            int k = ks * 32 + quad * 8 + j;
            int col = cg * 16 + l16;
            wt[idx] = f2bf(W[(size_t)k * 128 + col]);
        } else {                    // S2: OD=32, 4096 shorts
            int off = idx - 81920;
            int j = off & 7, l16 = (off >> 3) & 15, quad = (off >> 7) & 3;
            int cg = (off >> 9) & 1, ks = off >> 10;
            int k = ks * 32 + quad * 8 + j;
            int col = cg * 16 + l16;
            wt[idx] = f2bf(S2[(size_t)k * 32 + col]);
        }
        return;
    }
    int i = idx - WT_TOTAL;
    if (i < NN) deg[i] = 0;
}

// layer-0 dual GEMM + histogram, one dispatch.
// The block's 32-row fp32 x-tile is CONTIGUOUS (16 KB): stage it to LDS with
// fully-coalesced loads + in-register f2bf, then MFMA fragments from LDS.
// Histogram SAVES the atomic's return as rank[e] (coalesced stream) so
// k_scatter needs no cursor atomics.
__global__ __launch_bounds__(256) void k_gemm0_hist(
    const float* __restrict__ x,
    const unsigned short* __restrict__ Wta, const float* __restrict__ ba, unsigned short* __restrict__ ya,
    const unsigned short* __restrict__ Wtb, const float* __restrict__ bb, unsigned short* __restrict__ yb,
    const int* __restrict__ dst, int* __restrict__ deg, int* __restrict__ rank) {
    __shared__ unsigned short xt[32][136];
    __shared__ unsigned short tA[32][136];
    __shared__ unsigned short tB[32][136];
    int b = blockIdx.x;
    if (b < NG32) {
        int n0 = b * 32;
        // stage: 32 rows x 128 ch fp32 = 1024 float4; 256 threads x 4, coalesced
        #pragma unroll
        for (int s = 0; s < 4; ++s) {
            int i = s * 256 + threadIdx.x;
            int row = i >> 5, c4 = i & 31;
            int rr = (n0 + row < NN) ? n0 + row : NN - 1;
            float4 v = *(const float4*)&x[(size_t)rr * IN_DIM + c4 * 4];
            ushort4 pk = {f2bf(v.x), f2bf(v.y), f2bf(v.z), f2bf(v.w)};
            *(ushort4*)&xt[row][c4 * 4] = pk;
        }
        __syncthreads();
        int wid = threadIdx.x >> 6, lane = threadIdx.x & 63;
        if (wid < 2) {
            gemm16_lds<128, 4, 136, 136>(xt, Wta, ba, tA, wid * 4, lane);
            gemm16_lds<128, 4, 136, 136>(xt + 16, Wta, ba, tA + 16, wid * 4, lane);
        } else {
            gemm16_lds<128, 4, 136, 136>(xt, Wtb, bb, tB, (wid - 2) * 4, lane);
            gemm16_lds<128, 4, 136, 136>(xt + 16, Wtb, bb, tB + 16, (wid - 2) * 4, lane);
        }
        __syncthreads();
        int pt = threadIdx.x & 127;
        if (threadIdx.x < 128) store_tile128(tA, ya, n0, pt);
        else                   store_tile128(tB, yb, n0, pt);
    } else {
        int e = (b - NG32) * 256 + threadIdx.x;
        if (e < NE) rank[e] = atomicAdd(&deg[dst[e]], 1);
    }
}

__global__ __launch_bounds__(NTHR) void k_scan1(const int* __restrict__ deg,
                                                int* __restrict__ partial,
                                                int* __restrict__ blocksum) {
    __shared__ int sh[NTHR];
    int b = blockIdx.x, t = threadIdx.x;
    int i = b * NTHR + t;
    int d = (i < NN) ? deg[i] : 0;
    sh[t] = d;
    __syncthreads();
    #pragma unroll
    for (int off = 1; off < NTHR; off <<= 1) {
        int v = (t >= off) ? sh[t - off] : 0;
        __syncthreads();
        sh[t] += v;
        __syncthreads();
    }
    if (i < NN) partial[i] = sh[t];
    if (t == NTHR - 1) blocksum[b] = sh[t];
}

__global__ __launch_bounds__(NTHR) void k_scan23(const int* __restrict__ partial,
                                                 const int* __restrict__ blocksum,
                                                 int* __restrict__ rowptr) {
    __shared__ int sh[NTHR];
    int b = blockIdx.x, t = threadIdx.x;
    int v = (t < NTILE) ? blocksum[t] : 0;
    sh[t] = v;
    __syncthreads();
    #pragma unroll
    for (int off = 1; off < NTHR; off <<= 1) {
        int u = (t >= off) ? sh[t - off] : 0;
        __syncthreads();
        sh[t] += u;
        __syncthreads();
    }
    int tile_off = (b > 0) ? sh[b - 1] : 0;
    int i = b * NTHR + t;
    if (i < NN) {
        rowptr[i + 1] = partial[i] + tile_off;
        if (i == 0) rowptr[0] = 0;
    }
}

// atomic-free csr scatter: position = rowptr[dst] + rank (rank saved by the
// histogram's atomicAdd return). Entries premultiplied by HC.
__global__ void k_scatter(const int* __restrict__ src, const int* __restrict__ dst,
                          const int* __restrict__ rowptr, const int* __restrict__ rank,
                          int* __restrict__ csr_src) {
    int e = blockIdx.x * blockDim.x + threadIdx.x;
    if (e >= NE) return;
    int d = dst[e];
    csr_src[rowptr[d] + rank[e]] = src[e] * HC;
}

extern "C" void kernel_launch(void* const* d_in, const int* in_sizes, int n_in,
                              void* d_out, int out_size, void* d_ws, size_t ws_size,
                              hipStream_t stream) {
    const float* x0 = (const float*)d_in[0];
    const int* ei = (const int*)d_in[1];
    const int* src = ei;
    const int* dst = ei + NE;

    unsigned short* H0 = (unsigned short*)d_ws;              // NN*HC bf16
    unsigned short* S0 = H0 + (size_t)NN * HC;               // NN*HC bf16
    unsigned short* H1 = S0 + (size_t)NN * HC;               // NN*HC bf16
    unsigned short* S1 = H1 + (size_t)NN * HC;               // NN*HC bf16
    int* deg     = (int*)(S1 + (size_t)NN * HC);             // NN
    int* rowptr  = deg + NN;                                 // NN+1
    int* partial = rowptr + NN + 1;                          // NN
    int* blocksum = partial + NN;                            // NTILE
    int* rank    = blocksum + NTILE;                         // NE
    uintptr_t pa = (uintptr_t)(rank + NE);
    pa = (pa + 15) & ~(uintptr_t)15;
    unsigned short* wt = (unsigned short*)pa;                // WT_TOTAL bf16
    int* csr_src = (int*)(wt + WT_TOTAL);                    // NE

    unsigned short* wtW[3] = {wt, wt + 32768, wt + 65536};
    unsigned short* wtS[3] = {wt + 16384, wt + 49152, wt + 81920};

    // 1) prep: fragment-order transpose of weights, zero deg
    k_prep<<<(WT_TOTAL + NN + 255) / 256, 256, 0, stream>>>(
        (const float*)d_in[2], (const float*)d_in[6],
        (const float*)d_in[8], (const float*)d_in[12],
        (const float*)d_in[14], (const float*)d_in[18], wt, deg);

    // 2) layer-0 dual GEMM (LDS-staged coalesced x) + histogram (saves rank)
    k_gemm0_hist<<<NG32 + GHIST, 256, 0, stream>>>(
        x0, wtW[0], (const float*)d_in[3], H0,
        wtS[0], (const float*)d_in[7], S0, dst, deg, rank);

    // 3-5) CSR: scan, apply, atomic-free scatter
    k_scan1<<<NTILE, NTHR, 0, stream>>>(deg, partial, blocksum);
    k_scan23<<<NTILE, NTHR, 0, stream>>>(partial, blocksum, rowptr);
    k_scatter<<<GHIST, 256, 0, stream>>>(src, dst, rowptr, rank, csr_src);

    // 6) gat(l0) + gemm(l1) fused: reads H0/S0, writes H1/S1
    k_gat_gemm<128><<<NGAT16, 256, 0, stream>>>(
        H0, rowptr, csr_src,
        (const float*)d_in[4], (const float*)d_in[5], S0,
        wtW[1], (const float*)d_in[9], H1,
        wtS[1], (const float*)d_in[13], S1);

    // 7) gat(l1) + gemm(l2) fused: reads H1/S1, writes H0/S0 (skip 32-wide)
    k_gat_gemm<32><<<NGAT16, 256, 0, stream>>>(
        H1, rowptr, csr_src,
        (const float*)d_in[10], (const float*)d_in[11], S1,
        wtW[2], (const float*)d_in[15], H0,
        wtS[2], (const float*)d_in[19], S0);

    // 8) final gat(l2): head-mean + skip, fp32 out
    k_gat_last<<<NGAT16, 256, 0, stream>>>(
        H0, rowptr, csr_src,
        (const float*)d_in[16], (const float*)d_in[17], S0, (float*)d_out);
}